// Round 1
// baseline (325.583 us; speedup 1.0000x reference)
//
#include <hip/hip_runtime.h>
#include <math.h>

#define B_    4
#define L_    4096
#define DM    128
#define DI    256
#define DS    16
#define DTR   8
#define XPN   (DTR + 2*DS)   // 40
#define M_    (B_*L_)        // 16384
#define CHUNK 64
#define NC    (L_/CHUNK)     // 64
#define TT    16
#define LOG2E 1.4426950408889634f

// ---------------- K0: per-row rmsnorm scale ----------------
__global__ __launch_bounds__(256) void rms_scale_kernel(const float* __restrict__ x,
                                                        float* __restrict__ r) {
  int row  = blockIdx.x * 4 + (threadIdx.x >> 6);
  int lane = threadIdx.x & 63;
  const float* xp = x + (size_t)row * DM;
  float v0 = xp[lane], v1 = xp[lane + 64];
  float s = v0 * v0 + v1 * v1;
  #pragma unroll
  for (int off = 32; off > 0; off >>= 1) s += __shfl_down(s, off);
  if (lane == 0) r[row] = rsqrtf(s / DM + 1e-5f);
}

// ---------------- generic tiled fp32 GEMM ----------------
// C[M,N] = A[M,K] @ W[K,N]; optional per-row*per-k scaling of A (rmsnorm fold),
// optional +X residual on output.
template <int BM, int BN, int BK, bool SCALE_A, bool ADD_X>
__global__ __launch_bounds__(256) void gemm_kernel(const float* __restrict__ A,
                                                   const float* __restrict__ W,
                                                   float* __restrict__ C, int M, int N, int K,
                                                   const float* __restrict__ rs,
                                                   const float* __restrict__ cs,
                                                   const float* __restrict__ X) {
  constexpr int TM = 4, TN = 4;
  __shared__ float As[BK][BM + 1];
  __shared__ float Bs[BK][BN];
  const int tid  = threadIdx.x;
  const int tcol = tid & 15;   // 0..15
  const int trow = tid >> 4;   // 0..15
  const int row0 = blockIdx.x * BM;
  const int col0 = blockIdx.y * BN;
  float acc[TM][TN] = {};
  for (int k0 = 0; k0 < K; k0 += BK) {
    #pragma unroll
    for (int i = 0; i < (BM * BK) / 256; ++i) {
      int f = tid + i * 256, m = f / BK, k = f % BK;
      float v = A[(size_t)(row0 + m) * K + k0 + k];
      if (SCALE_A) v *= rs[row0 + m] * cs[k0 + k];
      As[k][m] = v;
    }
    #pragma unroll
    for (int i = 0; i < (BK * BN) / 256; ++i) {
      int f = tid + i * 256, k = f / BN, n = f % BN;
      Bs[k][n] = W[(size_t)(k0 + k) * N + col0 + n];
    }
    __syncthreads();
    #pragma unroll
    for (int k = 0; k < BK; ++k) {
      float a[TM], b[TN];
      #pragma unroll
      for (int i = 0; i < TM; ++i) a[i] = As[k][trow * TM + i];
      #pragma unroll
      for (int j = 0; j < TN; ++j) b[j] = Bs[k][tcol * TN + j];
      #pragma unroll
      for (int i = 0; i < TM; ++i)
        #pragma unroll
        for (int j = 0; j < TN; ++j) acc[i][j] = fmaf(a[i], b[j], acc[i][j]);
    }
    __syncthreads();
  }
  #pragma unroll
  for (int i = 0; i < TM; ++i) {
    int row = row0 + trow * TM + i;
    #pragma unroll
    for (int j = 0; j < TN; ++j) {
      int col = col0 + tcol * TN + j;
      float v = acc[i][j];
      if (ADD_X) v += X[(size_t)row * N + col];
      C[(size_t)row * N + col] = v;
    }
  }
}

// ---------------- conv1d (depthwise, causal, k=4) + SiLU ----------------
__global__ __launch_bounds__(256) void conv_silu_kernel(const float* __restrict__ xr,
                                                        const float* __restrict__ cw,
                                                        const float* __restrict__ cb,
                                                        float* __restrict__ xc) {
  int idx = blockIdx.x * 256 + threadIdx.x;  // over M_*DI
  int d  = idx & (DI - 1);
  int bl = idx >> 8;
  int l  = bl & (L_ - 1);
  float w0 = cw[d * 4 + 0], w1 = cw[d * 4 + 1], w2 = cw[d * 4 + 2], w3 = cw[d * 4 + 3];
  float s = cb[d];
  const float* base = xr + (size_t)bl * 512 + d;  // xi = xr[:, 0:256]
  if (l >= 3) s = fmaf(w0, base[-3 * 512], s);
  if (l >= 2) s = fmaf(w1, base[-2 * 512], s);
  if (l >= 1) s = fmaf(w2, base[-1 * 512], s);
  s = fmaf(w3, base[0], s);
  float sg = 1.f / (1.f + __expf(-s));
  xc[idx] = s * sg;
}

// ---------------- x_proj + dt_proj + softplus, fused ----------------
__global__ __launch_bounds__(256) void xproj_kernel(const float* __restrict__ xc,
                                                    const float* __restrict__ Wx,
                                                    const float* __restrict__ Wdt,
                                                    const float* __restrict__ bdt,
                                                    float* __restrict__ delta,
                                                    float* __restrict__ Bm,
                                                    float* __restrict__ Cm) {
  __shared__ float Wx_s[DI * XPN];   // 40 KB
  __shared__ float Wdt_s[DTR * DI];  // 8 KB
  __shared__ float A_s[8][DI];       // 8 KB
  __shared__ float xd_s[8][XPN + 1];
  const int tid  = threadIdx.x;
  const int row0 = blockIdx.x * 8;
  for (int i = tid; i < DI * XPN; i += 256) Wx_s[i] = Wx[i];
  for (int i = tid; i < DTR * DI; i += 256) Wdt_s[i] = Wdt[i];
  #pragma unroll
  for (int i = 0; i < 8; ++i) A_s[i][tid] = xc[(size_t)(row0 + i) * DI + tid];
  __syncthreads();
  for (int o = tid; o < 8 * XPN; o += 256) {
    int r = o / XPN, c = o % XPN;
    float acc = 0.f;
    #pragma unroll 8
    for (int k = 0; k < DI; ++k) acc = fmaf(A_s[r][k], Wx_s[k * XPN + c], acc);
    xd_s[r][c] = acc;
  }
  __syncthreads();
  if (tid < 128) {
    int r = tid >> 4, n = tid & 15;
    Bm[(size_t)(row0 + r) * DS + n] = xd_s[r][DTR + n];
    Cm[(size_t)(row0 + r) * DS + n] = xd_s[r][DTR + DS + n];
  }
  float bb = bdt[tid];
  #pragma unroll
  for (int r = 0; r < 8; ++r) {
    float acc = bb;
    #pragma unroll
    for (int k = 0; k < DTR; ++k) acc = fmaf(xd_s[r][k], Wdt_s[k * DI + tid], acc);
    float sp = (acc > 20.f) ? acc : log1pf(__expf(acc));
    delta[(size_t)(row0 + r) * DI + tid] = sp;
  }
}

// ---------------- scan phase A: per-chunk summaries ----------------
__global__ __launch_bounds__(256) void scanA_kernel(const float* __restrict__ delta,
                                                    const float* __restrict__ xc,
                                                    const float* __restrict__ Bm,
                                                    const float* __restrict__ Alog,
                                                    float* __restrict__ Ap,
                                                    float* __restrict__ Bg) {
  __shared__ float ds[TT][DI];
  __shared__ float xs[TT][DI];
  __shared__ float Bs[TT][DS];
  const int d = threadIdx.x;
  const int b = blockIdx.x / NC, c = blockIdx.x % NC;
  const size_t rowbase = (size_t)b * L_ + (size_t)c * CHUNK;
  float aln[DS];
  #pragma unroll
  for (int n = 0; n < DS; ++n) aln[n] = -__expf(Alog[d * DS + n]) * LOG2E;
  float P[DS], S[DS];
  #pragma unroll
  for (int n = 0; n < DS; ++n) { P[n] = 1.f; S[n] = 0.f; }
  for (int t0 = 0; t0 < CHUNK; t0 += TT) {
    #pragma unroll
    for (int i = 0; i < TT; ++i) ds[i][d] = delta[(rowbase + t0 + i) * DI + d];
    #pragma unroll
    for (int i = 0; i < TT; ++i) xs[i][d] = xc[(rowbase + t0 + i) * DI + d];
    ((float*)Bs)[d] = Bm[(rowbase + t0) * DS + d];
    __syncthreads();
    #pragma unroll
    for (int tt = 0; tt < TT; ++tt) {
      float dl = ds[tt][d];
      float du = dl * xs[tt][d];
      #pragma unroll
      for (int n = 0; n < DS; ++n) {
        float a = exp2f(dl * aln[n]);
        P[n] *= a;
        S[n] = fmaf(a, S[n], du * Bs[tt][n]);
      }
    }
    __syncthreads();
  }
  size_t ob = ((size_t)(b * NC + c) * DI + d) * DS;
  float4* po = (float4*)(Ap + ob);
  float4* so = (float4*)(Bg + ob);
  #pragma unroll
  for (int q = 0; q < 4; ++q) {
    po[q] = make_float4(P[4 * q], P[4 * q + 1], P[4 * q + 2], P[4 * q + 3]);
    so[q] = make_float4(S[4 * q], S[4 * q + 1], S[4 * q + 2], S[4 * q + 3]);
  }
}

// ---------------- scan phase B: scan over chunk summaries ----------------
__global__ __launch_bounds__(256) void scanB_kernel(const float* __restrict__ Ap,
                                                    const float* __restrict__ Bg,
                                                    float* __restrict__ sinit) {
  int g  = blockIdx.x * 256 + threadIdx.x;  // 0..16383 = (b, d, n)
  int b  = g >> 12;
  int dn = g & 4095;
  float s = 0.f;
  #pragma unroll 4
  for (int c = 0; c < NC; ++c) {
    size_t idx = ((size_t)(b * NC + c) << 12) + dn;
    sinit[idx] = s;
    s = fmaf(Ap[idx], s, Bg[idx]);
  }
}

// ---------------- scan phase C: replay with true init, emit y2 ----------------
__global__ __launch_bounds__(256) void scanC_kernel(const float* __restrict__ delta,
                                                    const float* __restrict__ xc,
                                                    const float* __restrict__ Bm,
                                                    const float* __restrict__ Cm,
                                                    const float* __restrict__ Alog,
                                                    const float* __restrict__ Dp,
                                                    const float* __restrict__ xr,
                                                    const float* __restrict__ sinit,
                                                    float* __restrict__ y2) {
  __shared__ float ds[TT][DI];
  __shared__ float xs[TT][DI];
  __shared__ float rs[TT][DI];
  __shared__ float Bs[TT][DS];
  __shared__ float Cs[TT][DS];
  const int d = threadIdx.x;
  const int b = blockIdx.x / NC, c = blockIdx.x % NC;
  const size_t rowbase = (size_t)b * L_ + (size_t)c * CHUNK;
  float aln[DS];
  #pragma unroll
  for (int n = 0; n < DS; ++n) aln[n] = -__expf(Alog[d * DS + n]) * LOG2E;
  const float Dd = Dp[d];
  float S[DS];
  {
    size_t ib = ((size_t)(b * NC + c) * DI + d) * DS;
    const float4* pi = (const float4*)(sinit + ib);
    #pragma unroll
    for (int q = 0; q < 4; ++q) {
      float4 v = pi[q];
      S[4 * q] = v.x; S[4 * q + 1] = v.y; S[4 * q + 2] = v.z; S[4 * q + 3] = v.w;
    }
  }
  for (int t0 = 0; t0 < CHUNK; t0 += TT) {
    #pragma unroll
    for (int i = 0; i < TT; ++i) ds[i][d] = delta[(rowbase + t0 + i) * DI + d];
    #pragma unroll
    for (int i = 0; i < TT; ++i) xs[i][d] = xc[(rowbase + t0 + i) * DI + d];
    #pragma unroll
    for (int i = 0; i < TT; ++i) rs[i][d] = xr[(rowbase + t0 + i) * 512 + 256 + d];
    ((float*)Bs)[d] = Bm[(rowbase + t0) * DS + d];
    ((float*)Cs)[d] = Cm[(rowbase + t0) * DS + d];
    __syncthreads();
    #pragma unroll
    for (int tt = 0; tt < TT; ++tt) {
      float dl = ds[tt][d];
      float xv = xs[tt][d];
      float du = dl * xv;
      float y = 0.f;
      #pragma unroll
      for (int n = 0; n < DS; ++n) {
        float a = exp2f(dl * aln[n]);
        S[n] = fmaf(a, S[n], du * Bs[tt][n]);
        y = fmaf(S[n], Cs[tt][n], y);
      }
      y = fmaf(xv, Dd, y);
      float rv = rs[tt][d];
      float sil = rv / (1.f + __expf(-rv));
      y2[(rowbase + t0 + tt) * DI + d] = y * sil;
    }
    __syncthreads();
  }
}

extern "C" void kernel_launch(void* const* d_in, const int* in_sizes, int n_in,
                              void* d_out, int out_size, void* d_ws, size_t ws_size,
                              hipStream_t stream) {
  const float* x      = (const float*)d_in[0];
  const float* norm_w = (const float*)d_in[1];
  const float* inW    = (const float*)d_in[2];
  const float* convw  = (const float*)d_in[3];
  const float* convb  = (const float*)d_in[4];
  const float* xprojw = (const float*)d_in[5];
  const float* dtw    = (const float*)d_in[6];
  const float* dtb    = (const float*)d_in[7];
  const float* alog   = (const float*)d_in[8];
  const float* Dp     = (const float*)d_in[9];
  const float* outw   = (const float*)d_in[10];
  float* out = (float*)d_out;

  float* ws    = (float*)d_ws;
  float* r     = ws;                    // 16384
  float* xr    = r + 16384;             // M_*512 = 8388608
  float* xc    = xr + (size_t)M_ * 512; // M_*256
  float* delta = xc + (size_t)M_ * DI;  // M_*256
  float* Bm    = delta + (size_t)M_ * DI;  // M_*16
  float* Cm    = Bm + (size_t)M_ * DS;     // M_*16
  float* Ap    = Cm + (size_t)M_ * DS;     // B_*NC*DI*DS = 1048576
  float* Bg    = Ap + (size_t)B_ * NC * DI * DS;
  float* sinit = Bg + (size_t)B_ * NC * DI * DS;
  float* y2    = sinit + (size_t)B_ * NC * DI * DS;  // M_*256

  // K0: rms scales
  rms_scale_kernel<<<M_ / 4, 256, 0, stream>>>(x, r);
  // G1: xr = (x * r * norm_w) @ inW   [16384x128 @ 128x512]
  gemm_kernel<64, 64, 16, true, false><<<dim3(M_ / 64, 512 / 64), 256, 0, stream>>>(
      x, inW, xr, M_, 512, DM, r, norm_w, nullptr);
  // K2: conv + silu -> xc
  conv_silu_kernel<<<(M_ * DI) / 256, 256, 0, stream>>>(xr, convw, convb, xc);
  // K3: x_proj + dt_proj + softplus -> delta, Bm, Cm
  xproj_kernel<<<M_ / 8, 256, 0, stream>>>(xc, xprojw, dtw, dtb, delta, Bm, Cm);
  // scan
  scanA_kernel<<<B_ * NC, 256, 0, stream>>>(delta, xc, Bm, alog, Ap, Bg);
  scanB_kernel<<<(B_ * DI * DS) / 256, 256, 0, stream>>>(Ap, Bg, sinit);
  scanC_kernel<<<B_ * NC, 256, 0, stream>>>(delta, xc, Bm, Cm, alog, Dp, xr, sinit, y2);
  // G5: out = y2 @ outw + x   [16384x256 @ 256x128]
  gemm_kernel<64, 64, 16, false, true><<<dim3(M_ / 64, DM / 64), 256, 0, stream>>>(
      y2, outw, out, M_, DM, DI, nullptr, nullptr, x);
}

// Round 2
// 261.762 us; speedup vs baseline: 1.2438x; 1.2438x over previous
//
#include <hip/hip_runtime.h>
#include <math.h>

#define B_    4
#define L_    4096
#define DM    128
#define DI    256
#define DS    16
#define DTR   8
#define XPN   (DTR + 2*DS)   // 40
#define M_    (B_*L_)        // 16384
#define CHUNK 32
#define NC    (L_/CHUNK)     // 128
#define LOG2E 1.4426950408889634f

// ---------------- K0: per-row rmsnorm scale ----------------
__global__ __launch_bounds__(256) void rms_scale_kernel(const float* __restrict__ x,
                                                        float* __restrict__ r) {
  int row  = blockIdx.x * 4 + (threadIdx.x >> 6);
  int lane = threadIdx.x & 63;
  const float* xp = x + (size_t)row * DM;
  float v0 = xp[lane], v1 = xp[lane + 64];
  float s = v0 * v0 + v1 * v1;
  #pragma unroll
  for (int off = 32; off > 0; off >>= 1) s += __shfl_down(s, off);
  if (lane == 0) r[row] = rsqrtf(s / DM + 1e-5f);
}

// ---------------- generic tiled fp32 GEMM ----------------
// C[M,N] = A[M,K] @ W[K,N] (A has leading dim lda); optional per-row*per-k
// scaling of A (rmsnorm fold), optional +X residual on output.
template <int BM, int BN, int BK, bool SCALE_A, bool ADD_X>
__global__ __launch_bounds__(256) void gemm_kernel(const float* __restrict__ A,
                                                   const float* __restrict__ W,
                                                   float* __restrict__ C, int M, int N, int K,
                                                   int lda,
                                                   const float* __restrict__ rs,
                                                   const float* __restrict__ cs,
                                                   const float* __restrict__ X) {
  constexpr int TM = 4, TN = 4;
  __shared__ float As[BK][BM + 1];
  __shared__ float Bs[BK][BN];
  const int tid  = threadIdx.x;
  const int tcol = tid & 15;   // 0..15
  const int trow = tid >> 4;   // 0..15
  const int row0 = blockIdx.x * BM;
  const int col0 = blockIdx.y * BN;
  float acc[TM][TN] = {};
  for (int k0 = 0; k0 < K; k0 += BK) {
    #pragma unroll
    for (int i = 0; i < (BM * BK) / 256; ++i) {
      int f = tid + i * 256, m = f / BK, k = f % BK;
      float v = A[(size_t)(row0 + m) * lda + k0 + k];
      if (SCALE_A) v *= rs[row0 + m] * cs[k0 + k];
      As[k][m] = v;
    }
    #pragma unroll
    for (int i = 0; i < (BK * BN) / 256; ++i) {
      int f = tid + i * 256, k = f / BN, n = f % BN;
      Bs[k][n] = W[(size_t)(k0 + k) * N + col0 + n];
    }
    __syncthreads();
    #pragma unroll
    for (int k = 0; k < BK; ++k) {
      float a[TM], b[TN];
      #pragma unroll
      for (int i = 0; i < TM; ++i) a[i] = As[k][trow * TM + i];
      #pragma unroll
      for (int j = 0; j < TN; ++j) b[j] = Bs[k][tcol * TN + j];
      #pragma unroll
      for (int i = 0; i < TM; ++i)
        #pragma unroll
        for (int j = 0; j < TN; ++j) acc[i][j] = fmaf(a[i], b[j], acc[i][j]);
    }
    __syncthreads();
  }
  #pragma unroll
  for (int i = 0; i < TM; ++i) {
    int row = row0 + trow * TM + i;
    #pragma unroll
    for (int j = 0; j < TN; ++j) {
      int col = col0 + tcol * TN + j;
      float v = acc[i][j];
      if (ADD_X) v += X[(size_t)row * N + col];
      C[(size_t)row * N + col] = v;
    }
  }
}

// ---------------- conv1d (depthwise, causal, k=4) + SiLU ----------------
__global__ __launch_bounds__(256) void conv_silu_kernel(const float* __restrict__ xr,
                                                        const float* __restrict__ cw,
                                                        const float* __restrict__ cb,
                                                        float* __restrict__ xc) {
  int idx = blockIdx.x * 256 + threadIdx.x;  // over M_*DI
  int d  = idx & (DI - 1);
  int bl = idx >> 8;
  int l  = bl & (L_ - 1);
  float w0 = cw[d * 4 + 0], w1 = cw[d * 4 + 1], w2 = cw[d * 4 + 2], w3 = cw[d * 4 + 3];
  float s = cb[d];
  const float* base = xr + (size_t)bl * 512 + d;  // xi = xr[:, 0:256]
  if (l >= 3) s = fmaf(w0, base[-3 * 512], s);
  if (l >= 2) s = fmaf(w1, base[-2 * 512], s);
  if (l >= 1) s = fmaf(w2, base[-1 * 512], s);
  s = fmaf(w3, base[0], s);
  float sg = 1.f / (1.f + __expf(-s));
  xc[idx] = s * sg;
}

// ---------------- x_proj + dt_proj + softplus, fused ----------------
__global__ __launch_bounds__(256) void xproj_kernel(const float* __restrict__ xc,
                                                    const float* __restrict__ Wx,
                                                    const float* __restrict__ Wdt,
                                                    const float* __restrict__ bdt,
                                                    float* __restrict__ delta,
                                                    float* __restrict__ Bm,
                                                    float* __restrict__ Cm) {
  __shared__ float Wx_s[DI * XPN];   // 40 KB
  __shared__ float Wdt_s[DTR * DI];  // 8 KB
  __shared__ float A_s[8][DI];       // 8 KB
  __shared__ float xd_s[8][XPN + 1];
  const int tid  = threadIdx.x;
  const int row0 = blockIdx.x * 8;
  for (int i = tid; i < DI * XPN; i += 256) Wx_s[i] = Wx[i];
  for (int i = tid; i < DTR * DI; i += 256) Wdt_s[i] = Wdt[i];
  #pragma unroll
  for (int i = 0; i < 8; ++i) A_s[i][tid] = xc[(size_t)(row0 + i) * DI + tid];
  __syncthreads();
  for (int o = tid; o < 8 * XPN; o += 256) {
    int r = o / XPN, c = o % XPN;
    float acc = 0.f;
    #pragma unroll 8
    for (int k = 0; k < DI; ++k) acc = fmaf(A_s[r][k], Wx_s[k * XPN + c], acc);
    xd_s[r][c] = acc;
  }
  __syncthreads();
  if (tid < 128) {
    int r = tid >> 4, n = tid & 15;
    Bm[(size_t)(row0 + r) * DS + n] = xd_s[r][DTR + n];
    Cm[(size_t)(row0 + r) * DS + n] = xd_s[r][DTR + DS + n];
  }
  float bb = bdt[tid];
  #pragma unroll
  for (int r = 0; r < 8; ++r) {
    float acc = bb;
    #pragma unroll
    for (int k = 0; k < DTR; ++k) acc = fmaf(xd_s[r][k], Wdt_s[k * DI + tid], acc);
    float sp = (acc > 20.f) ? acc : log1pf(__expf(acc));
    delta[(size_t)(row0 + r) * DI + tid] = sp;
  }
}

// ---------------- scan phase A: per-chunk summaries (P = prod a, S = partial scan) ----
__global__ __launch_bounds__(256) void scanA_kernel(const float* __restrict__ delta,
                                                    const float* __restrict__ xc,
                                                    const float* __restrict__ Bm,
                                                    const float* __restrict__ Alog,
                                                    float* __restrict__ Ap,
                                                    float* __restrict__ Bg) {
  __shared__ float Bs[CHUNK][DS];  // 2 KB
  const int d = threadIdx.x;
  const int b = blockIdx.x / NC, c = blockIdx.x % NC;
  const size_t rowbase = (size_t)b * L_ + (size_t)c * CHUNK;
  // stage B chunk (contiguous CHUNK*DS floats)
  #pragma unroll
  for (int i = d; i < CHUNK * DS; i += 256) ((float*)Bs)[i] = Bm[rowbase * DS + i];
  float aln[DS];
  #pragma unroll
  for (int n = 0; n < DS; ++n) aln[n] = -__expf(Alog[d * DS + n]) * LOG2E;
  // geometric-ladder fast path detection: aln[n] == (n+1)*aln[0]?
  bool geom = true;
  #pragma unroll
  for (int n = 1; n < DS; ++n)
    geom = geom && (fabsf(aln[n] - (n + 1) * aln[0]) <= 1e-3f * fabsf(aln[n]));
  float P[DS], S[DS];
  #pragma unroll
  for (int n = 0; n < DS; ++n) { P[n] = 1.f; S[n] = 0.f; }
  __syncthreads();
  for (int t0 = 0; t0 < CHUNK; t0 += 8) {
    float dl[8], xv[8];
    #pragma unroll
    for (int i = 0; i < 8; ++i) dl[i] = delta[(rowbase + t0 + i) * DI + d];
    #pragma unroll
    for (int i = 0; i < 8; ++i) xv[i] = xc[(rowbase + t0 + i) * DI + d];
    if (geom) {
      #pragma unroll
      for (int i = 0; i < 8; ++i) {
        float du = dl[i] * xv[i];
        float e1 = exp2f(dl[i] * aln[0]);
        float a = 1.f;
        #pragma unroll
        for (int n = 0; n < DS; ++n) {
          a *= e1;
          P[n] *= a;
          S[n] = fmaf(a, S[n], du * Bs[t0 + i][n]);
        }
      }
    } else {
      #pragma unroll
      for (int i = 0; i < 8; ++i) {
        float du = dl[i] * xv[i];
        #pragma unroll
        for (int n = 0; n < DS; ++n) {
          float a = exp2f(dl[i] * aln[n]);
          P[n] *= a;
          S[n] = fmaf(a, S[n], du * Bs[t0 + i][n]);
        }
      }
    }
  }
  size_t ob = ((size_t)(b * NC + c) * DI + d) * DS;
  float4* po = (float4*)(Ap + ob);
  float4* so = (float4*)(Bg + ob);
  #pragma unroll
  for (int q = 0; q < 4; ++q) {
    po[q] = make_float4(P[4 * q], P[4 * q + 1], P[4 * q + 2], P[4 * q + 3]);
    so[q] = make_float4(S[4 * q], S[4 * q + 1], S[4 * q + 2], S[4 * q + 3]);
  }
}

// ---------------- scan phase B: scan over chunk summaries ----------------
__global__ __launch_bounds__(64) void scanB_kernel(const float* __restrict__ Ap,
                                                   const float* __restrict__ Bg,
                                                   float* __restrict__ sinit) {
  int g  = blockIdx.x * 64 + threadIdx.x;  // 0..16383 = (b, d, n)
  int b  = g >> 12;
  int dn = g & 4095;
  float s = 0.f;
  #pragma unroll 8
  for (int c = 0; c < NC; ++c) {
    size_t idx = ((size_t)(b * NC + c) << 12) + dn;
    sinit[idx] = s;
    s = fmaf(Ap[idx], s, Bg[idx]);
  }
}

// ---------------- scan phase C: replay with true init, emit y2 (into xi half of xr) ----
__global__ __launch_bounds__(256) void scanC_kernel(const float* __restrict__ delta,
                                                    const float* __restrict__ xc,
                                                    const float* __restrict__ Bm,
                                                    const float* __restrict__ Cm,
                                                    const float* __restrict__ Alog,
                                                    const float* __restrict__ Dp,
                                                    float* __restrict__ xr,
                                                    const float* __restrict__ sinit) {
  __shared__ float Bs[CHUNK][DS];
  __shared__ float Cs[CHUNK][DS];
  const int d = threadIdx.x;
  const int b = blockIdx.x / NC, c = blockIdx.x % NC;
  const size_t rowbase = (size_t)b * L_ + (size_t)c * CHUNK;
  #pragma unroll
  for (int i = d; i < CHUNK * DS; i += 256) {
    ((float*)Bs)[i] = Bm[rowbase * DS + i];
    ((float*)Cs)[i] = Cm[rowbase * DS + i];
  }
  float aln[DS];
  #pragma unroll
  for (int n = 0; n < DS; ++n) aln[n] = -__expf(Alog[d * DS + n]) * LOG2E;
  bool geom = true;
  #pragma unroll
  for (int n = 1; n < DS; ++n)
    geom = geom && (fabsf(aln[n] - (n + 1) * aln[0]) <= 1e-3f * fabsf(aln[n]));
  const float Dd = Dp[d];
  float S[DS];
  {
    size_t ib = ((size_t)(b * NC + c) * DI + d) * DS;
    const float4* pi = (const float4*)(sinit + ib);
    #pragma unroll
    for (int q = 0; q < 4; ++q) {
      float4 v = pi[q];
      S[4 * q] = v.x; S[4 * q + 1] = v.y; S[4 * q + 2] = v.z; S[4 * q + 3] = v.w;
    }
  }
  __syncthreads();
  for (int t0 = 0; t0 < CHUNK; t0 += 8) {
    float dl[8], xv[8], rv[8];
    #pragma unroll
    for (int i = 0; i < 8; ++i) dl[i] = delta[(rowbase + t0 + i) * DI + d];
    #pragma unroll
    for (int i = 0; i < 8; ++i) xv[i] = xc[(rowbase + t0 + i) * DI + d];
    #pragma unroll
    for (int i = 0; i < 8; ++i) rv[i] = xr[(rowbase + t0 + i) * 512 + 256 + d];
    #pragma unroll
    for (int i = 0; i < 8; ++i) {
      float du = dl[i] * xv[i];
      float y = 0.f;
      if (geom) {
        float e1 = exp2f(dl[i] * aln[0]);
        float a = 1.f;
        #pragma unroll
        for (int n = 0; n < DS; ++n) {
          a *= e1;
          S[n] = fmaf(a, S[n], du * Bs[t0 + i][n]);
          y = fmaf(S[n], Cs[t0 + i][n], y);
        }
      } else {
        #pragma unroll
        for (int n = 0; n < DS; ++n) {
          float a = exp2f(dl[i] * aln[n]);
          S[n] = fmaf(a, S[n], du * Bs[t0 + i][n]);
          y = fmaf(S[n], Cs[t0 + i][n], y);
        }
      }
      y = fmaf(xv[i], Dd, y);
      float sil = rv[i] / (1.f + __expf(-rv[i]));
      xr[(rowbase + t0 + i) * 512 + d] = y * sil;  // y2 into dead xi slot
    }
  }
}

extern "C" void kernel_launch(void* const* d_in, const int* in_sizes, int n_in,
                              void* d_out, int out_size, void* d_ws, size_t ws_size,
                              hipStream_t stream) {
  const float* x      = (const float*)d_in[0];
  const float* norm_w = (const float*)d_in[1];
  const float* inW    = (const float*)d_in[2];
  const float* convw  = (const float*)d_in[3];
  const float* convb  = (const float*)d_in[4];
  const float* xprojw = (const float*)d_in[5];
  const float* dtw    = (const float*)d_in[6];
  const float* dtb    = (const float*)d_in[7];
  const float* alog   = (const float*)d_in[8];
  const float* Dp     = (const float*)d_in[9];
  const float* outw   = (const float*)d_in[10];
  float* out = (float*)d_out;

  float* ws    = (float*)d_ws;
  float* r     = ws;                       // 16384
  float* xr    = r + 16384;                // M_*512
  float* xc    = xr + (size_t)M_ * 512;    // M_*256
  float* delta = xc + (size_t)M_ * DI;     // M_*256
  float* Bm    = delta + (size_t)M_ * DI;  // M_*16
  float* Cm    = Bm + (size_t)M_ * DS;     // M_*16
  float* Ap    = Cm + (size_t)M_ * DS;     // B_*NC*DI*DS = 2097152
  float* Bg    = Ap + (size_t)B_ * NC * DI * DS;
  float* sinit = Bg + (size_t)B_ * NC * DI * DS;
  // y2 aliased into xi half of xr

  rms_scale_kernel<<<M_ / 4, 256, 0, stream>>>(x, r);
  gemm_kernel<64, 64, 16, true, false><<<dim3(M_ / 64, 512 / 64), 256, 0, stream>>>(
      x, inW, xr, M_, 512, DM, DM, r, norm_w, nullptr);
  conv_silu_kernel<<<(M_ * DI) / 256, 256, 0, stream>>>(xr, convw, convb, xc);
  xproj_kernel<<<M_ / 8, 256, 0, stream>>>(xc, xprojw, dtw, dtb, delta, Bm, Cm);
  scanA_kernel<<<B_ * NC, 256, 0, stream>>>(delta, xc, Bm, alog, Ap, Bg);
  scanB_kernel<<<(B_ * DI * DS) / 64, 64, 0, stream>>>(Ap, Bg, sinit);
  scanC_kernel<<<B_ * NC, 256, 0, stream>>>(delta, xc, Bm, Cm, alog, Dp, xr, sinit);
  gemm_kernel<64, 64, 16, false, true><<<dim3(M_ / 64, DM / 64), 256, 0, stream>>>(
      xr, outw, out, M_, DM, DI, 512, nullptr, nullptr, x);
}

// Round 3
// 251.788 us; speedup vs baseline: 1.2931x; 1.0396x over previous
//
#include <hip/hip_runtime.h>
#include <math.h>

#define B_    4
#define L_    4096
#define DM    128
#define DI    256
#define DS    16
#define DTR   8
#define XPN   (DTR + 2*DS)   // 40
#define NB    (DI + 2*DS)    // 288 fused xproj output cols
#define M_    (B_*L_)        // 16384
#define CHUNK 32
#define NC    (L_/CHUNK)     // 128
#define LOG2E 1.4426950408889634f

// ---------------- K0: per-row rmsnorm scale ----------------
__global__ __launch_bounds__(256) void rms_scale_kernel(const float* __restrict__ x,
                                                        float* __restrict__ r) {
  int row  = blockIdx.x * 4 + (threadIdx.x >> 6);
  int lane = threadIdx.x & 63;
  const float* xp = x + (size_t)row * DM;
  float v0 = xp[lane], v1 = xp[lane + 64];
  float s = v0 * v0 + v1 * v1;
  #pragma unroll
  for (int off = 32; off > 0; off >>= 1) s += __shfl_down(s, off);
  if (lane == 0) r[row] = rsqrtf(s / DM + 1e-5f);
}

// ---------------- generic tiled fp32 GEMM (float4 staging, b128 LDS reads) ----
// C[M,N] = A[M,K] @ W[K,N] (A leading dim lda); optional rmsnorm fold on A,
// optional +X residual. BM=64, BN=64, BK=16, 256 threads, 4x4 microtile.
template <bool SCALE_A, bool ADD_X>
__global__ __launch_bounds__(256) void gemm_kernel(const float* __restrict__ A,
                                                   const float* __restrict__ W,
                                                   float* __restrict__ C, int M, int N, int K,
                                                   int lda,
                                                   const float* __restrict__ rs,
                                                   const float* __restrict__ cs,
                                                   const float* __restrict__ X) {
  constexpr int BM = 64, BN = 64, BK = 16;
  __shared__ __align__(16) float As[BK][BM + 4];  // stride 68: rows 16B-aligned
  __shared__ __align__(16) float Bs[BK][BN];
  const int tid  = threadIdx.x;
  const int tcol = tid & 15;   // 0..15
  const int trow = tid >> 4;   // 0..15
  const int row0 = blockIdx.x * BM;
  const int col0 = blockIdx.y * BN;
  float acc[4][4] = {};
  for (int k0 = 0; k0 < K; k0 += BK) {
    // A stage: 64x16 = 256 float4, 1/thread
    {
      int m = tid >> 2, kq = tid & 3;
      float4 v = *(const float4*)(A + (size_t)(row0 + m) * lda + k0 + 4 * kq);
      if (SCALE_A) {
        float rr = rs[row0 + m];
        float4 c4 = *(const float4*)(cs + k0 + 4 * kq);
        v.x *= rr * c4.x; v.y *= rr * c4.y; v.z *= rr * c4.z; v.w *= rr * c4.w;
      }
      As[4 * kq + 0][m] = v.x; As[4 * kq + 1][m] = v.y;
      As[4 * kq + 2][m] = v.z; As[4 * kq + 3][m] = v.w;
    }
    // W stage: 16x64 = 256 float4, 1/thread
    {
      int k = tid >> 4, n4 = tid & 15;
      *(float4*)(&Bs[k][4 * n4]) = *(const float4*)(W + (size_t)(k0 + k) * N + col0 + 4 * n4);
    }
    __syncthreads();
    #pragma unroll
    for (int k = 0; k < BK; ++k) {
      float4 a4 = *(const float4*)(&As[k][trow * 4]);
      float4 b4 = *(const float4*)(&Bs[k][tcol * 4]);
      float a[4] = {a4.x, a4.y, a4.z, a4.w};
      float b[4] = {b4.x, b4.y, b4.z, b4.w};
      #pragma unroll
      for (int i = 0; i < 4; ++i)
        #pragma unroll
        for (int j = 0; j < 4; ++j) acc[i][j] = fmaf(a[i], b[j], acc[i][j]);
    }
    __syncthreads();
  }
  #pragma unroll
  for (int i = 0; i < 4; ++i) {
    int row = row0 + trow * 4 + i;
    float4 o = make_float4(acc[i][0], acc[i][1], acc[i][2], acc[i][3]);
    if (ADD_X) {
      float4 xv = *(const float4*)(X + (size_t)row * N + col0 + tcol * 4);
      o.x += xv.x; o.y += xv.y; o.z += xv.z; o.w += xv.w;
    }
    *(float4*)(C + (size_t)row * N + col0 + tcol * 4) = o;
  }
}

// ---------------- build Wbig[256 x 288] = [Wx[:,:8]@Wdt | Wx[:,8:40]] ------
__global__ __launch_bounds__(256) void fuse_w_kernel(const float* __restrict__ Wx,
                                                     const float* __restrict__ Wdt,
                                                     float* __restrict__ Wbig) {
  int k = blockIdx.x;  // 0..255
  int tid = threadIdx.x;
  float wj[DTR];
  #pragma unroll
  for (int j = 0; j < DTR; ++j) wj[j] = Wx[k * XPN + j];
  for (int c = tid; c < NB; c += 256) {
    float v;
    if (c < DI) {
      v = 0.f;
      #pragma unroll
      for (int j = 0; j < DTR; ++j) v = fmaf(wj[j], Wdt[j * DI + c], v);
    } else {
      v = Wx[k * XPN + DTR + (c - DI)];
    }
    Wbig[(size_t)k * NB + c] = v;
  }
}

// ---------------- xproj as GEMM: xc[16384x256] @ Wbig[256x288] -------------
// epilogue: cols<256 -> softplus(v+bdt) -> delta; 256..271 -> Bm; 272..287 -> Cm
__global__ __launch_bounds__(256) void xproj_gemm_kernel(const float* __restrict__ A,
                                                         const float* __restrict__ W,
                                                         const float* __restrict__ bdt,
                                                         float* __restrict__ delta,
                                                         float* __restrict__ Bm,
                                                         float* __restrict__ Cm) {
  constexpr int BM = 128, BN = 32, BK = 32;
  __shared__ __align__(16) float As[BK][BM + 4];  // stride 132: rows 16B-aligned
  __shared__ __align__(16) float Bs[BK][BN];
  const int tid  = threadIdx.x;
  const int tcol = tid & 7;    // 0..7  (x4 -> 32 cols)
  const int trow = tid >> 3;   // 0..31 (x4 -> 128 rows)
  const int row0 = blockIdx.x * BM;
  const int col0 = blockIdx.y * BN;
  float acc[4][4] = {};
  for (int k0 = 0; k0 < DI; k0 += BK) {
    // A stage: 128x32 = 1024 float4, 4/thread
    #pragma unroll
    for (int i = 0; i < 4; ++i) {
      int q = tid + i * 256;
      int m = q >> 3, kq = q & 7;
      float4 v = *(const float4*)(A + (size_t)(row0 + m) * DI + k0 + 4 * kq);
      As[4 * kq + 0][m] = v.x; As[4 * kq + 1][m] = v.y;
      As[4 * kq + 2][m] = v.z; As[4 * kq + 3][m] = v.w;
    }
    // W stage: 32x32 = 256 float4, 1/thread
    {
      int k = tid >> 3, n4 = tid & 7;
      *(float4*)(&Bs[k][4 * n4]) = *(const float4*)(W + (size_t)(k0 + k) * NB + col0 + 4 * n4);
    }
    __syncthreads();
    #pragma unroll
    for (int k = 0; k < BK; ++k) {
      float4 a4 = *(const float4*)(&As[k][trow * 4]);
      float4 b4 = *(const float4*)(&Bs[k][tcol * 4]);
      float a[4] = {a4.x, a4.y, a4.z, a4.w};
      float b[4] = {b4.x, b4.y, b4.z, b4.w};
      #pragma unroll
      for (int i = 0; i < 4; ++i)
        #pragma unroll
        for (int j = 0; j < 4; ++j) acc[i][j] = fmaf(a[i], b[j], acc[i][j]);
    }
    __syncthreads();
  }
  const int row = row0 + trow * 4;
  if (col0 < DI) {  // delta block (uniform: col0+31 < 256 for blockIdx.y < 8)
    float4 b4 = *(const float4*)(bdt + col0 + tcol * 4);
    float bb[4] = {b4.x, b4.y, b4.z, b4.w};
    #pragma unroll
    for (int i = 0; i < 4; ++i) {
      float o[4];
      #pragma unroll
      for (int j = 0; j < 4; ++j) {
        float v = acc[i][j] + bb[j];
        o[j] = (v > 20.f) ? v : log1pf(__expf(v));
      }
      *(float4*)(delta + (size_t)(row + i) * DI + col0 + tcol * 4) =
          make_float4(o[0], o[1], o[2], o[3]);
    }
  } else {  // B/C block: tcol<4 -> Bm, else Cm
    float* dst = (tcol < 4) ? Bm : Cm;
    int cb = (tcol < 4) ? tcol * 4 : tcol * 4 - 16;
    #pragma unroll
    for (int i = 0; i < 4; ++i) {
      *(float4*)(dst + (size_t)(row + i) * DS + cb) =
          make_float4(acc[i][0], acc[i][1], acc[i][2], acc[i][3]);
    }
  }
}

// ---------------- conv1d (depthwise, causal, k=4) + SiLU ----------------
__global__ __launch_bounds__(256) void conv_silu_kernel(const float* __restrict__ xr,
                                                        const float* __restrict__ cw,
                                                        const float* __restrict__ cb,
                                                        float* __restrict__ xc) {
  int idx = blockIdx.x * 256 + threadIdx.x;  // over M_*DI
  int d  = idx & (DI - 1);
  int bl = idx >> 8;
  int l  = bl & (L_ - 1);
  float w0 = cw[d * 4 + 0], w1 = cw[d * 4 + 1], w2 = cw[d * 4 + 2], w3 = cw[d * 4 + 3];
  float s = cb[d];
  const float* base = xr + (size_t)bl * 512 + d;  // xi = xr[:, 0:256]
  if (l >= 3) s = fmaf(w0, base[-3 * 512], s);
  if (l >= 2) s = fmaf(w1, base[-2 * 512], s);
  if (l >= 1) s = fmaf(w2, base[-1 * 512], s);
  s = fmaf(w3, base[0], s);
  float sg = 1.f / (1.f + __expf(-s));
  xc[idx] = s * sg;
}

// ---------------- scan phase A: per-chunk summaries ----------------
__global__ __launch_bounds__(256) void scanA_kernel(const float* __restrict__ delta,
                                                    const float* __restrict__ xc,
                                                    const float* __restrict__ Bm,
                                                    const float* __restrict__ Alog,
                                                    float* __restrict__ Ap,
                                                    float* __restrict__ Bg) {
  __shared__ float Bs[CHUNK][DS];  // 2 KB
  const int d = threadIdx.x;
  const int b = blockIdx.x / NC, c = blockIdx.x % NC;
  const size_t rowbase = (size_t)b * L_ + (size_t)c * CHUNK;
  #pragma unroll
  for (int i = d; i < CHUNK * DS; i += 256) ((float*)Bs)[i] = Bm[rowbase * DS + i];
  float aln[DS];
  #pragma unroll
  for (int n = 0; n < DS; ++n) aln[n] = -__expf(Alog[d * DS + n]) * LOG2E;
  bool geom = true;
  #pragma unroll
  for (int n = 1; n < DS; ++n)
    geom = geom && (fabsf(aln[n] - (n + 1) * aln[0]) <= 1e-3f * fabsf(aln[n]));
  float P[DS], S[DS];
  #pragma unroll
  for (int n = 0; n < DS; ++n) { P[n] = 1.f; S[n] = 0.f; }
  __syncthreads();
  for (int t0 = 0; t0 < CHUNK; t0 += 8) {
    float dl[8], xv[8];
    #pragma unroll
    for (int i = 0; i < 8; ++i) dl[i] = delta[(rowbase + t0 + i) * DI + d];
    #pragma unroll
    for (int i = 0; i < 8; ++i) xv[i] = xc[(rowbase + t0 + i) * DI + d];
    if (geom) {
      #pragma unroll
      for (int i = 0; i < 8; ++i) {
        float du = dl[i] * xv[i];
        float e1 = exp2f(dl[i] * aln[0]);
        float a = 1.f;
        #pragma unroll
        for (int n = 0; n < DS; ++n) {
          a *= e1;
          P[n] *= a;
          S[n] = fmaf(a, S[n], du * Bs[t0 + i][n]);
        }
      }
    } else {
      #pragma unroll
      for (int i = 0; i < 8; ++i) {
        float du = dl[i] * xv[i];
        #pragma unroll
        for (int n = 0; n < DS; ++n) {
          float a = exp2f(dl[i] * aln[n]);
          P[n] *= a;
          S[n] = fmaf(a, S[n], du * Bs[t0 + i][n]);
        }
      }
    }
  }
  size_t ob = ((size_t)(b * NC + c) * DI + d) * DS;
  float4* po = (float4*)(Ap + ob);
  float4* so = (float4*)(Bg + ob);
  #pragma unroll
  for (int q = 0; q < 4; ++q) {
    po[q] = make_float4(P[4 * q], P[4 * q + 1], P[4 * q + 2], P[4 * q + 3]);
    so[q] = make_float4(S[4 * q], S[4 * q + 1], S[4 * q + 2], S[4 * q + 3]);
  }
}

// ---------------- scan phase B: scan over chunk summaries ----------------
__global__ __launch_bounds__(64) void scanB_kernel(const float* __restrict__ Ap,
                                                   const float* __restrict__ Bg,
                                                   float* __restrict__ sinit) {
  int g  = blockIdx.x * 64 + threadIdx.x;  // 0..16383 = (b, d, n)
  int b  = g >> 12;
  int dn = g & 4095;
  float s = 0.f;
  #pragma unroll 8
  for (int c = 0; c < NC; ++c) {
    size_t idx = ((size_t)(b * NC + c) << 12) + dn;
    sinit[idx] = s;
    s = fmaf(Ap[idx], s, Bg[idx]);
  }
}

// ---------------- scan phase C: replay with true init, emit y2 into xi slot ----
__global__ __launch_bounds__(256) void scanC_kernel(const float* __restrict__ delta,
                                                    const float* __restrict__ xc,
                                                    const float* __restrict__ Bm,
                                                    const float* __restrict__ Cm,
                                                    const float* __restrict__ Alog,
                                                    const float* __restrict__ Dp,
                                                    float* __restrict__ xr,
                                                    const float* __restrict__ sinit) {
  __shared__ float Bs[CHUNK][DS];
  __shared__ float Cs[CHUNK][DS];
  const int d = threadIdx.x;
  const int b = blockIdx.x / NC, c = blockIdx.x % NC;
  const size_t rowbase = (size_t)b * L_ + (size_t)c * CHUNK;
  #pragma unroll
  for (int i = d; i < CHUNK * DS; i += 256) {
    ((float*)Bs)[i] = Bm[rowbase * DS + i];
    ((float*)Cs)[i] = Cm[rowbase * DS + i];
  }
  float aln[DS];
  #pragma unroll
  for (int n = 0; n < DS; ++n) aln[n] = -__expf(Alog[d * DS + n]) * LOG2E;
  bool geom = true;
  #pragma unroll
  for (int n = 1; n < DS; ++n)
    geom = geom && (fabsf(aln[n] - (n + 1) * aln[0]) <= 1e-3f * fabsf(aln[n]));
  const float Dd = Dp[d];
  float S[DS];
  {
    size_t ib = ((size_t)(b * NC + c) * DI + d) * DS;
    const float4* pi = (const float4*)(sinit + ib);
    #pragma unroll
    for (int q = 0; q < 4; ++q) {
      float4 v = pi[q];
      S[4 * q] = v.x; S[4 * q + 1] = v.y; S[4 * q + 2] = v.z; S[4 * q + 3] = v.w;
    }
  }
  __syncthreads();
  for (int t0 = 0; t0 < CHUNK; t0 += 8) {
    float dl[8], xv[8], rv[8];
    #pragma unroll
    for (int i = 0; i < 8; ++i) dl[i] = delta[(rowbase + t0 + i) * DI + d];
    #pragma unroll
    for (int i = 0; i < 8; ++i) xv[i] = xc[(rowbase + t0 + i) * DI + d];
    #pragma unroll
    for (int i = 0; i < 8; ++i) rv[i] = xr[(rowbase + t0 + i) * 512 + 256 + d];
    #pragma unroll
    for (int i = 0; i < 8; ++i) {
      float du = dl[i] * xv[i];
      float y = 0.f;
      if (geom) {
        float e1 = exp2f(dl[i] * aln[0]);
        float a = 1.f;
        #pragma unroll
        for (int n = 0; n < DS; ++n) {
          a *= e1;
          S[n] = fmaf(a, S[n], du * Bs[t0 + i][n]);
          y = fmaf(S[n], Cs[t0 + i][n], y);
        }
      } else {
        #pragma unroll
        for (int n = 0; n < DS; ++n) {
          float a = exp2f(dl[i] * aln[n]);
          S[n] = fmaf(a, S[n], du * Bs[t0 + i][n]);
          y = fmaf(S[n], Cs[t0 + i][n], y);
        }
      }
      y = fmaf(xv[i], Dd, y);
      float sil = rv[i] / (1.f + __expf(-rv[i]));
      xr[(rowbase + t0 + i) * 512 + d] = y * sil;  // y2 into dead xi slot
    }
  }
}

extern "C" void kernel_launch(void* const* d_in, const int* in_sizes, int n_in,
                              void* d_out, int out_size, void* d_ws, size_t ws_size,
                              hipStream_t stream) {
  const float* x      = (const float*)d_in[0];
  const float* norm_w = (const float*)d_in[1];
  const float* inW    = (const float*)d_in[2];
  const float* convw  = (const float*)d_in[3];
  const float* convb  = (const float*)d_in[4];
  const float* xprojw = (const float*)d_in[5];
  const float* dtw    = (const float*)d_in[6];
  const float* dtb    = (const float*)d_in[7];
  const float* alog   = (const float*)d_in[8];
  const float* Dp     = (const float*)d_in[9];
  const float* outw   = (const float*)d_in[10];
  float* out = (float*)d_out;

  float* ws    = (float*)d_ws;
  float* r     = ws;                       // 16384
  float* xr    = r + 16384;                // M_*512
  float* xc    = xr + (size_t)M_ * 512;    // M_*256
  float* delta = xc + (size_t)M_ * DI;     // M_*256
  float* Bm    = delta + (size_t)M_ * DI;  // M_*16
  float* Cm    = Bm + (size_t)M_ * DS;     // M_*16
  float* Ap    = Cm + (size_t)M_ * DS;     // B_*NC*DI*DS
  float* Bg    = Ap + (size_t)B_ * NC * DI * DS;
  float* sinit = Bg + (size_t)B_ * NC * DI * DS;
  float* Wbig  = sinit + (size_t)B_ * NC * DI * DS;  // 256*288

  fuse_w_kernel<<<DI, 256, 0, stream>>>(xprojw, dtw, Wbig);
  rms_scale_kernel<<<M_ / 4, 256, 0, stream>>>(x, r);
  gemm_kernel<true, false><<<dim3(M_ / 64, 512 / 64), 256, 0, stream>>>(
      x, inW, xr, M_, 512, DM, DM, r, norm_w, nullptr);
  conv_silu_kernel<<<(M_ * DI) / 256, 256, 0, stream>>>(xr, convw, convb, xc);
  xproj_gemm_kernel<<<dim3(M_ / 128, NB / 32), 256, 0, stream>>>(
      xc, Wbig, dtb, delta, Bm, Cm);
  scanA_kernel<<<B_ * NC, 256, 0, stream>>>(delta, xc, Bm, alog, Ap, Bg);
  scanB_kernel<<<(B_ * DI * DS) / 64, 64, 0, stream>>>(Ap, Bg, sinit);
  scanC_kernel<<<B_ * NC, 256, 0, stream>>>(delta, xc, Bm, Cm, alog, Dp, xr, sinit);
  gemm_kernel<false, true><<<dim3(M_ / 64, DM / 64), 256, 0, stream>>>(
      xr, outw, out, M_, DM, DI, 512, nullptr, nullptr, x);
}

// Round 4
// 190.430 us; speedup vs baseline: 1.7097x; 1.3222x over previous
//
#include <hip/hip_runtime.h>
#include <math.h>

#define B_    4
#define L_    4096
#define DM    128
#define DI    256
#define DS    16
#define DTR   8
#define XPN   (DTR + 2*DS)   // 40
#define NB    (DI + 2*DS)    // 288 fused xproj output cols
#define M_    (B_*L_)        // 16384
#define CHUNK 32
#define NC    (L_/CHUNK)     // 128
#define LOG2E 1.4426950408889634f

typedef __attribute__((ext_vector_type(8))) short bf16x8;   // 8 bf16 = 4 VGPR
typedef __attribute__((ext_vector_type(4))) float f32x4;    // MFMA acc
typedef unsigned short ushort_t;

__device__ __forceinline__ ushort_t f2bf(float f) {  // fp32 -> bf16 RNE
  unsigned int u = __float_as_uint(f);
  u += 0x7FFFu + ((u >> 16) & 1u);
  return (ushort_t)(u >> 16);
}

// ---------------- prep: all weights -> bf16, transposed [N][K]; fuse dtproj ----
// inWt[512][128] <- inW[128][512]; WbigT[288][256] <- [Wx[:, :8]@Wdt | Wx[:,8:40]]^T;
// outWt[128][256] <- outw[256][128]
__global__ __launch_bounds__(256) void prep_w_kernel(const float* __restrict__ inW,
                                                     const float* __restrict__ Wx,
                                                     const float* __restrict__ Wdt,
                                                     const float* __restrict__ outw,
                                                     ushort_t* __restrict__ inWt,
                                                     ushort_t* __restrict__ WbigT,
                                                     ushort_t* __restrict__ outWt) {
  int g = blockIdx.x * 256 + threadIdx.x;
  if (g < 512 * 128) {
    int n = g >> 7, k = g & 127;
    inWt[g] = f2bf(inW[k * 512 + n]);
  } else if (g < 512 * 128 + NB * DI) {
    int q = g - 512 * 128;
    int c = q >> 8, k = q & 255;
    float v;
    if (c < DI) {
      v = 0.f;
      #pragma unroll
      for (int j = 0; j < DTR; ++j) v = fmaf(Wx[k * XPN + j], Wdt[j * DI + c], v);
    } else {
      v = Wx[k * XPN + DTR + (c - DI)];
    }
    WbigT[q] = f2bf(v);
  } else if (g < 512 * 128 + NB * DI + DM * DI) {
    int q = g - (512 * 128 + NB * DI);
    int n = q >> 8, k = q & 255;
    outWt[q] = f2bf(outw[k * DM + n]);
  }
}

// ---------------- rmsnorm -> bf16 normalized activations --------------------
__global__ __launch_bounds__(256) void rms_bf16_kernel(const float* __restrict__ x,
                                                       const float* __restrict__ nw,
                                                       ushort_t* __restrict__ xbf) {
  int row  = blockIdx.x * 4 + (threadIdx.x >> 6);
  int lane = threadIdx.x & 63;
  const float* xp = x + (size_t)row * DM;
  float v0 = xp[lane], v1 = xp[lane + 64];
  float s = v0 * v0 + v1 * v1;
  #pragma unroll
  for (int off = 32; off > 0; off >>= 1) s += __shfl_xor(s, off);
  float r = rsqrtf(s / DM + 1e-5f);
  ushort_t* op = xbf + (size_t)row * DM;
  op[lane]      = f2bf(v0 * r * nw[lane]);
  op[lane + 64] = f2bf(v1 * r * nw[lane + 64]);
}

// ---------------- bf16 MFMA GEMM: C[M,N] = A[M,K] @ Wt[N,K]^T ---------------
// BM=128, BK=64, 4 waves; wave w: rows w*32..w*32+31, all BN cols.
// EPI 0: C fp32 (ldc).  EPI 1: xproj epilogue (delta/Bm/Cm).  EPI 2: C = acc + X.
template <int BN, int EPI>
__global__ __launch_bounds__(256) void gemm_mfma_kernel(const ushort_t* __restrict__ A,
                                                        const ushort_t* __restrict__ Wt,
                                                        float* __restrict__ C, int K, int ldc,
                                                        const float* __restrict__ bdt,
                                                        float* __restrict__ Bm,
                                                        float* __restrict__ Cm,
                                                        const float* __restrict__ X) {
  constexpr int BM = 128, BK = 64, NT = BN / 16;
  // k-block-major: [kb][m][8] so frag reads and staging writes are b128,
  // +1 row padding -> bank stride 4 per kb: conflict-free stages & 2-way reads.
  __shared__ __align__(16) ushort_t Asm[BK / 8][BM + 1][8];
  __shared__ __align__(16) ushort_t Bsm[BK / 8][BN + 1][8];
  const int tid  = threadIdx.x;
  const int wave = tid >> 6, lane = tid & 63;
  const int quad = lane >> 4, l16 = lane & 15;
  const int row0 = blockIdx.x * BM;
  const int col0 = blockIdx.y * BN;
  f32x4 acc[2][NT];
  #pragma unroll
  for (int mt = 0; mt < 2; ++mt)
    #pragma unroll
    for (int nt = 0; nt < NT; ++nt) acc[mt][nt] = (f32x4){0.f, 0.f, 0.f, 0.f};

  for (int k0 = 0; k0 < K; k0 += BK) {
    #pragma unroll
    for (int i = 0; i < 4; ++i) {  // A: 128x64 bf16 = 1024 b128
      int q = tid + i * 256;
      int m = q >> 3, kb = q & 7;
      *(bf16x8*)(&Asm[kb][m][0]) =
          *(const bf16x8*)(A + (size_t)(row0 + m) * K + k0 + kb * 8);
    }
    #pragma unroll
    for (int i = 0; i < (BN * 8) / 256; ++i) {  // B: BNx64 bf16
      int q = tid + i * 256;
      int n = q >> 3, kb = q & 7;
      *(bf16x8*)(&Bsm[kb][n][0]) =
          *(const bf16x8*)(Wt + (size_t)(col0 + n) * K + k0 + kb * 8);
    }
    __syncthreads();
    #pragma unroll
    for (int ks = 0; ks < 2; ++ks) {  // two K=32 mfma steps per BK=64
      bf16x8 af[2], bfr[NT];
      #pragma unroll
      for (int mt = 0; mt < 2; ++mt)
        af[mt] = *(const bf16x8*)(&Asm[ks * 4 + quad][wave * 32 + mt * 16 + l16][0]);
      #pragma unroll
      for (int nt = 0; nt < NT; ++nt)
        bfr[nt] = *(const bf16x8*)(&Bsm[ks * 4 + quad][nt * 16 + l16][0]);
      #pragma unroll
      for (int mt = 0; mt < 2; ++mt)
        #pragma unroll
        for (int nt = 0; nt < NT; ++nt)
          acc[mt][nt] = __builtin_amdgcn_mfma_f32_16x16x32_bf16(af[mt], bfr[nt],
                                                                acc[mt][nt], 0, 0, 0);
    }
    __syncthreads();
  }
  // epilogue: acc elem r -> (row = base + quad*4 + r, col = col0 + nt*16 + l16)
  #pragma unroll
  for (int mt = 0; mt < 2; ++mt) {
    #pragma unroll
    for (int nt = 0; nt < NT; ++nt) {
      int col   = col0 + nt * 16 + l16;
      int rbase = row0 + wave * 32 + mt * 16 + quad * 4;
      if (EPI == 0) {
        #pragma unroll
        for (int r = 0; r < 4; ++r)
          C[(size_t)(rbase + r) * ldc + col] = acc[mt][nt][r];
      } else if (EPI == 1) {
        if (col < DI) {
          float bb = bdt[col];
          #pragma unroll
          for (int r = 0; r < 4; ++r) {
            float v = acc[mt][nt][r] + bb;
            C[(size_t)(rbase + r) * DI + col] = (v > 20.f) ? v : log1pf(__expf(v));
          }
        } else if (col < DI + DS) {
          #pragma unroll
          for (int r = 0; r < 4; ++r)
            Bm[(size_t)(rbase + r) * DS + (col - DI)] = acc[mt][nt][r];
        } else {
          #pragma unroll
          for (int r = 0; r < 4; ++r)
            Cm[(size_t)(rbase + r) * DS + (col - DI - DS)] = acc[mt][nt][r];
        }
      } else {
        #pragma unroll
        for (int r = 0; r < 4; ++r)
          C[(size_t)(rbase + r) * ldc + col] =
              acc[mt][nt][r] + X[(size_t)(rbase + r) * ldc + col];
      }
    }
  }
}

// ---------------- conv1d (depthwise, causal, k=4) + SiLU -> xc fp32 + bf16 ----
__global__ __launch_bounds__(256) void conv_silu_kernel(const float* __restrict__ xr,
                                                        const float* __restrict__ cw,
                                                        const float* __restrict__ cb,
                                                        float* __restrict__ xc,
                                                        ushort_t* __restrict__ xcbf) {
  int idx = blockIdx.x * 256 + threadIdx.x;  // over M_*DI
  int d  = idx & (DI - 1);
  int bl = idx >> 8;
  int l  = bl & (L_ - 1);
  float w0 = cw[d * 4 + 0], w1 = cw[d * 4 + 1], w2 = cw[d * 4 + 2], w3 = cw[d * 4 + 3];
  float s = cb[d];
  const float* base = xr + (size_t)bl * 512 + d;  // xi = xr[:, 0:256]
  if (l >= 3) s = fmaf(w0, base[-3 * 512], s);
  if (l >= 2) s = fmaf(w1, base[-2 * 512], s);
  if (l >= 1) s = fmaf(w2, base[-1 * 512], s);
  s = fmaf(w3, base[0], s);
  float sg = 1.f / (1.f + __expf(-s));
  float v = s * sg;
  xc[idx] = v;
  xcbf[idx] = f2bf(v);
}

// ---------------- scan phase A: per-chunk summaries ----------------
__global__ __launch_bounds__(256) void scanA_kernel(const float* __restrict__ delta,
                                                    const float* __restrict__ xc,
                                                    const float* __restrict__ Bm,
                                                    const float* __restrict__ Alog,
                                                    float* __restrict__ Ap,
                                                    float* __restrict__ Bg) {
  __shared__ float Bs[CHUNK][DS];  // 2 KB
  const int d = threadIdx.x;
  const int b = blockIdx.x / NC, c = blockIdx.x % NC;
  const size_t rowbase = (size_t)b * L_ + (size_t)c * CHUNK;
  #pragma unroll
  for (int i = d; i < CHUNK * DS; i += 256) ((float*)Bs)[i] = Bm[rowbase * DS + i];
  float aln[DS];
  #pragma unroll
  for (int n = 0; n < DS; ++n) aln[n] = -__expf(Alog[d * DS + n]) * LOG2E;
  bool geom = true;
  #pragma unroll
  for (int n = 1; n < DS; ++n)
    geom = geom && (fabsf(aln[n] - (n + 1) * aln[0]) <= 1e-3f * fabsf(aln[n]));
  float P[DS], S[DS];
  #pragma unroll
  for (int n = 0; n < DS; ++n) { P[n] = 1.f; S[n] = 0.f; }
  __syncthreads();
  for (int t0 = 0; t0 < CHUNK; t0 += 8) {
    float dl[8], xv[8];
    #pragma unroll
    for (int i = 0; i < 8; ++i) dl[i] = delta[(rowbase + t0 + i) * DI + d];
    #pragma unroll
    for (int i = 0; i < 8; ++i) xv[i] = xc[(rowbase + t0 + i) * DI + d];
    if (geom) {
      #pragma unroll
      for (int i = 0; i < 8; ++i) {
        float du = dl[i] * xv[i];
        float e1 = exp2f(dl[i] * aln[0]);
        float a = 1.f;
        #pragma unroll
        for (int n = 0; n < DS; ++n) {
          a *= e1;
          P[n] *= a;
          S[n] = fmaf(a, S[n], du * Bs[t0 + i][n]);
        }
      }
    } else {
      #pragma unroll
      for (int i = 0; i < 8; ++i) {
        float du = dl[i] * xv[i];
        #pragma unroll
        for (int n = 0; n < DS; ++n) {
          float a = exp2f(dl[i] * aln[n]);
          P[n] *= a;
          S[n] = fmaf(a, S[n], du * Bs[t0 + i][n]);
        }
      }
    }
  }
  size_t ob = ((size_t)(b * NC + c) * DI + d) * DS;
  float4* po = (float4*)(Ap + ob);
  float4* so = (float4*)(Bg + ob);
  #pragma unroll
  for (int q = 0; q < 4; ++q) {
    po[q] = make_float4(P[4 * q], P[4 * q + 1], P[4 * q + 2], P[4 * q + 3]);
    so[q] = make_float4(S[4 * q], S[4 * q + 1], S[4 * q + 2], S[4 * q + 3]);
  }
}

// ---------------- scan phase B: scan over chunk summaries ----------------
__global__ __launch_bounds__(64) void scanB_kernel(const float* __restrict__ Ap,
                                                   const float* __restrict__ Bg,
                                                   float* __restrict__ sinit) {
  int g  = blockIdx.x * 64 + threadIdx.x;  // 0..16383 = (b, d, n)
  int b  = g >> 12;
  int dn = g & 4095;
  float s = 0.f;
  #pragma unroll 8
  for (int c = 0; c < NC; ++c) {
    size_t idx = ((size_t)(b * NC + c) << 12) + dn;
    sinit[idx] = s;
    s = fmaf(Ap[idx], s, Bg[idx]);
  }
}

// ---------------- scan phase C: replay with true init, emit y2 (bf16) -------
__global__ __launch_bounds__(256) void scanC_kernel(const float* __restrict__ delta,
                                                    const float* __restrict__ xc,
                                                    const float* __restrict__ Bm,
                                                    const float* __restrict__ Cm,
                                                    const float* __restrict__ Alog,
                                                    const float* __restrict__ Dp,
                                                    const float* __restrict__ xr,
                                                    const float* __restrict__ sinit,
                                                    ushort_t* __restrict__ y2bf) {
  __shared__ float Bs[CHUNK][DS];
  __shared__ float Cs[CHUNK][DS];
  const int d = threadIdx.x;
  const int b = blockIdx.x / NC, c = blockIdx.x % NC;
  const size_t rowbase = (size_t)b * L_ + (size_t)c * CHUNK;
  #pragma unroll
  for (int i = d; i < CHUNK * DS; i += 256) {
    ((float*)Bs)[i] = Bm[rowbase * DS + i];
    ((float*)Cs)[i] = Cm[rowbase * DS + i];
  }
  float aln[DS];
  #pragma unroll
  for (int n = 0; n < DS; ++n) aln[n] = -__expf(Alog[d * DS + n]) * LOG2E;
  bool geom = true;
  #pragma unroll
  for (int n = 1; n < DS; ++n)
    geom = geom && (fabsf(aln[n] - (n + 1) * aln[0]) <= 1e-3f * fabsf(aln[n]));
  const float Dd = Dp[d];
  float S[DS];
  {
    size_t ib = ((size_t)(b * NC + c) * DI + d) * DS;
    const float4* pi = (const float4*)(sinit + ib);
    #pragma unroll
    for (int q = 0; q < 4; ++q) {
      float4 v = pi[q];
      S[4 * q] = v.x; S[4 * q + 1] = v.y; S[4 * q + 2] = v.z; S[4 * q + 3] = v.w;
    }
  }
  __syncthreads();
  for (int t0 = 0; t0 < CHUNK; t0 += 8) {
    float dl[8], xv[8], rv[8];
    #pragma unroll
    for (int i = 0; i < 8; ++i) dl[i] = delta[(rowbase + t0 + i) * DI + d];
    #pragma unroll
    for (int i = 0; i < 8; ++i) xv[i] = xc[(rowbase + t0 + i) * DI + d];
    #pragma unroll
    for (int i = 0; i < 8; ++i) rv[i] = xr[(rowbase + t0 + i) * 512 + 256 + d];
    #pragma unroll
    for (int i = 0; i < 8; ++i) {
      float du = dl[i] * xv[i];
      float y = 0.f;
      if (geom) {
        float e1 = exp2f(dl[i] * aln[0]);
        float a = 1.f;
        #pragma unroll
        for (int n = 0; n < DS; ++n) {
          a *= e1;
          S[n] = fmaf(a, S[n], du * Bs[t0 + i][n]);
          y = fmaf(S[n], Cs[t0 + i][n], y);
        }
      } else {
        #pragma unroll
        for (int n = 0; n < DS; ++n) {
          float a = exp2f(dl[i] * aln[n]);
          S[n] = fmaf(a, S[n], du * Bs[t0 + i][n]);
          y = fmaf(S[n], Cs[t0 + i][n], y);
        }
      }
      y = fmaf(xv[i], Dd, y);
      float sil = rv[i] / (1.f + __expf(-rv[i]));
      y2bf[(rowbase + t0 + i) * DI + d] = f2bf(y * sil);
    }
  }
}

extern "C" void kernel_launch(void* const* d_in, const int* in_sizes, int n_in,
                              void* d_out, int out_size, void* d_ws, size_t ws_size,
                              hipStream_t stream) {
  const float* x      = (const float*)d_in[0];
  const float* norm_w = (const float*)d_in[1];
  const float* inW    = (const float*)d_in[2];
  const float* convw  = (const float*)d_in[3];
  const float* convb  = (const float*)d_in[4];
  const float* xprojw = (const float*)d_in[5];
  const float* dtw    = (const float*)d_in[6];
  const float* dtb    = (const float*)d_in[7];
  const float* alog   = (const float*)d_in[8];
  const float* Dp     = (const float*)d_in[9];
  const float* outw   = (const float*)d_in[10];
  float* out = (float*)d_out;

  const size_t CS = (size_t)B_ * NC * DI * DS;  // 2,097,152
  float* ws    = (float*)d_ws;
  float* xr    = ws;                        // M_*512 fp32
  float* xc    = xr + (size_t)M_ * 512;     // M_*256 fp32
  float* delta = xc + (size_t)M_ * DI;      // M_*256 fp32
  float* Bmv   = delta + (size_t)M_ * DI;   // M_*16
  float* Cmv   = Bmv + (size_t)M_ * DS;     // M_*16
  float* Ap    = Cmv + (size_t)M_ * DS;     // CS  (later aliased as y2bf)
  float* Bg    = Ap + CS;                   // CS
  float* sinit = Bg + CS;                   // CS
  // bf16 region: xbf (M_*128) lives in same region as xcbf (M_*256) — xbf dead
  // before conv writes xcbf. y2bf aliases Ap (dead after scanB).
  ushort_t* bfbase = (ushort_t*)(sinit + CS);
  ushort_t* xbf    = bfbase;
  ushort_t* xcbf   = bfbase;                       // M_*256 ushorts
  ushort_t* inWt   = bfbase + (size_t)M_ * DI;     // 512*128
  ushort_t* WbigT  = inWt + 512 * 128;             // 288*256
  ushort_t* outWt  = WbigT + NB * DI;              // 128*256
  ushort_t* y2bf   = (ushort_t*)Ap;                // M_*256 ushorts (= CS floats)

  prep_w_kernel<<<(512 * 128 + NB * DI + DM * DI + 255) / 256, 256, 0, stream>>>(
      inW, xprojw, dtw, outw, inWt, WbigT, outWt);
  rms_bf16_kernel<<<M_ / 4, 256, 0, stream>>>(x, norm_w, xbf);
  // G1: xr[16384x512] = xbf[16384x128] @ inWt^T
  gemm_mfma_kernel<64, 0><<<dim3(M_ / 128, 512 / 64), 256, 0, stream>>>(
      xbf, inWt, xr, DM, 512, nullptr, nullptr, nullptr, nullptr);
  conv_silu_kernel<<<(M_ * DI) / 256, 256, 0, stream>>>(xr, convw, convb, xc, xcbf);
  // xproj: delta/Bm/Cm from xcbf[16384x256] @ WbigT^T (N=288)
  gemm_mfma_kernel<32, 1><<<dim3(M_ / 128, NB / 32), 256, 0, stream>>>(
      xcbf, WbigT, delta, DI, DI, dtb, Bmv, Cmv, nullptr);
  scanA_kernel<<<B_ * NC, 256, 0, stream>>>(delta, xc, Bmv, alog, Ap, Bg);
  scanB_kernel<<<(B_ * DI * DS) / 64, 64, 0, stream>>>(Ap, Bg, sinit);
  scanC_kernel<<<B_ * NC, 256, 0, stream>>>(delta, xc, Bmv, Cmv, alog, Dp, xr, sinit, y2bf);
  // G2: out[16384x128] = y2bf @ outWt^T + x
  gemm_mfma_kernel<32, 2><<<dim3(M_ / 128, DM / 32), 256, 0, stream>>>(
      y2bf, outWt, out, DI, DM, nullptr, nullptr, nullptr, x);
}